// Round 1
// baseline (346.845 us; speedup 1.0000x reference)
//
#include <hip/hip_runtime.h>
#include <hip/hip_bf16.h>

// Problem constants
#define Nn   32
#define Ee   512
#define DIN  300
#define DOUT 300
#define NT   4
#define QD   300
#define SLOPE 0.2f
#define ROWS 32   // rows per block in attn kernel

// ---------------------------------------------------------------------------
// K1: gates. g[i][n][0..599] = sigmoid( relu(q[n] @ W1[i]) @ W2[i] )
// grid (NT, N), block 256
__global__ __launch_bounds__(256) void gates_kernel(
    const float* __restrict__ q,    // (N, 300)
    const float* __restrict__ W1,   // (4, 300, 600)
    const float* __restrict__ W2,   // (4, 600, 600)
    float* __restrict__ g)          // (4, N, 600)
{
    int i = blockIdx.x;
    int n = blockIdx.y;
    int tid = threadIdx.x;
    __shared__ float qs[QD];
    __shared__ float t1[2 * DOUT];

    for (int k = tid; k < QD; k += 256) qs[k] = q[n * QD + k];
    __syncthreads();

    const float* W1i = W1 + (size_t)i * QD * (2 * DOUT);
    for (int j = tid; j < 2 * DOUT; j += 256) {
        float acc = 0.f;
        for (int k = 0; k < QD; ++k) acc += qs[k] * W1i[k * (2 * DOUT) + j];
        t1[j] = fmaxf(acc, 0.f);
    }
    __syncthreads();

    const float* W2i = W2 + (size_t)i * (2 * DOUT) * (2 * DOUT);
    for (int j = tid; j < 2 * DOUT; j += 256) {
        float acc = 0.f;
        for (int k = 0; k < 2 * DOUT; ++k) acc += t1[k] * W2i[k * (2 * DOUT) + j];
        g[((size_t)i * Nn + n) * (2 * DOUT) + j] = 1.f / (1.f + __expf(-acc));
    }
}

// ---------------------------------------------------------------------------
// K2: u1[i][n][k] = sum_d W[i][k][d] * g1[i][n][d] * a1[i][d]  (u2 same with g2,a2)
// grid (NT, N), block 256
__global__ __launch_bounds__(256) void uvec_kernel(
    const float* __restrict__ W,    // (4, 300, 300)
    const float* __restrict__ a,    // (4, 600)
    const float* __restrict__ g,    // (4, N, 600)
    float* __restrict__ u1,         // (4, N, 300)
    float* __restrict__ u2)         // (4, N, 300)
{
    int i = blockIdx.x;
    int n = blockIdx.y;
    int tid = threadIdx.x;
    __shared__ float w1[DOUT], w2[DOUT];

    const float* gi = g + ((size_t)i * Nn + n) * (2 * DOUT);
    const float* ai = a + (size_t)i * (2 * DOUT);
    for (int d = tid; d < DOUT; d += 256) {
        w1[d] = gi[d] * ai[d];
        w2[d] = gi[DOUT + d] * ai[DOUT + d];
    }
    __syncthreads();

    const float* Wi = W + (size_t)i * DIN * DOUT;
    for (int k = tid; k < DIN; k += 256) {
        float a1 = 0.f, a2 = 0.f;
        for (int d = 0; d < DOUT; ++d) {
            float w = Wi[k * DOUT + d];
            a1 += w * w1[d];
            a2 += w * w2[d];
        }
        u1[((size_t)i * Nn + n) * DIN + k] = a1;
        u2[((size_t)i * Nn + n) * DIN + k] = a2;
    }
}

// ---------------------------------------------------------------------------
// K3: ssrc[i][n][e] = input[n,e,:] . u1[i][n][:]   (sdst with u2)
// grid (E, N), block 64 (one wave per (n,e))
__global__ __launch_bounds__(64) void sdot_kernel(
    const float* __restrict__ X,    // (N, E, 300)
    const float* __restrict__ u1,   // (4, N, 300)
    const float* __restrict__ u2,   // (4, N, 300)
    float* __restrict__ ssrc,       // (4, N, E)
    float* __restrict__ sdst)       // (4, N, E)
{
    int e = blockIdx.x;
    int n = blockIdx.y;
    int lane = threadIdx.x;
    const float* x = X + ((size_t)n * Ee + e) * DIN;

    float xv[5];
    #pragma unroll
    for (int k = 0; k < 5; ++k) {
        int d = lane + 64 * k;
        xv[k] = (d < DIN) ? x[d] : 0.f;
    }
    #pragma unroll
    for (int i = 0; i < NT; ++i) {
        const float* u1i = u1 + ((size_t)i * Nn + n) * DIN;
        const float* u2i = u2 + ((size_t)i * Nn + n) * DIN;
        float a1 = 0.f, a2 = 0.f;
        #pragma unroll
        for (int k = 0; k < 5; ++k) {
            int d = lane + 64 * k;
            if (d < DIN) { a1 += xv[k] * u1i[d]; a2 += xv[k] * u2i[d]; }
        }
        #pragma unroll
        for (int off = 32; off; off >>= 1) {
            a1 += __shfl_xor(a1, off);
            a2 += __shfl_xor(a2, off);
        }
        if (lane == 0) {
            ssrc[((size_t)i * Nn + n) * Ee + e] = a1;
            sdst[((size_t)i * Nn + n) * Ee + e] = a2;
        }
    }
}

// ---------------------------------------------------------------------------
// K4: hm[row][d] = (X[row,:] @ W3)[d] * mask[row]     rows = N*E = 16384
// grid 512, block 256 (4 waves, each wave 8 rows x all 300 d)
__global__ __launch_bounds__(256) void hm_kernel(
    const float* __restrict__ X,    // (16384, 300)
    const float* __restrict__ W3,   // (300, 300)
    const float* __restrict__ mask, // (16384)
    float* __restrict__ hm)         // (16384, 300)
{
    __shared__ float Xs[32 * DIN];
    int tid = threadIdx.x;
    size_t row0 = (size_t)blockIdx.x * 32;

    for (int idx = tid; idx < 32 * DIN; idx += 256)
        Xs[idx] = X[row0 * DIN + idx];
    __syncthreads();

    int wv = tid >> 6, lane = tid & 63;
    int r0 = wv * 8;
    float acc[8][5];
    #pragma unroll
    for (int r = 0; r < 8; ++r)
        #pragma unroll
        for (int k = 0; k < 5; ++k) acc[r][k] = 0.f;

    for (int kk = 0; kk < DIN; ++kk) {
        float wval[5];
        #pragma unroll
        for (int k = 0; k < 5; ++k) {
            int d = lane + 64 * k;
            wval[k] = (d < DOUT) ? W3[kk * DOUT + d] : 0.f;
        }
        #pragma unroll
        for (int r = 0; r < 8; ++r) {
            float x = Xs[(r0 + r) * DIN + kk];
            #pragma unroll
            for (int k = 0; k < 5; ++k) acc[r][k] += x * wval[k];
        }
    }

    #pragma unroll
    for (int r = 0; r < 8; ++r) {
        float mk = mask[row0 + r0 + r];
        #pragma unroll
        for (int k = 0; k < 5; ++k) {
            int d = lane + 64 * k;
            if (d < DOUT) hm[(row0 + r0 + r) * DOUT + d] = acc[r][k] * mk;
        }
    }
}

// ---------------------------------------------------------------------------
// K5: fused scores -> softmax -> PV for a tile of 32 rows of batch n.
// grid (E/ROWS, N), block 256 (4 waves; each wave owns 8 rows)
__global__ __launch_bounds__(256) void attn_kernel(
    const int*   __restrict__ adj,  // (N, E, E)
    const float* __restrict__ ssrc, // (4, N, E)
    const float* __restrict__ sdst, // (4, N, E)
    const float* __restrict__ hm,   // (N, E, 300)
    float* __restrict__ out)        // (N, E, 300)
{
    int rt = blockIdx.x;
    int n  = blockIdx.y;
    int tid = threadIdx.x;
    int row0 = rt * ROWS;

    __shared__ float sd[NT][Ee];
    __shared__ float ss[NT][ROWS];
    __shared__ float coef[ROWS][Ee];

    for (int idx = tid; idx < NT * Ee; idx += 256) {
        int i = idx >> 9, j = idx & (Ee - 1);
        sd[i][j] = sdst[((size_t)i * Nn + n) * Ee + j];
    }
    for (int idx = tid; idx < NT * ROWS; idx += 256) {
        int i = idx / ROWS, r = idx % ROWS;
        ss[i][r] = ssrc[((size_t)i * Nn + n) * Ee + row0 + r];
    }
    __syncthreads();

    // scores
    const int* adjb = adj + ((size_t)n * Ee + row0) * Ee;
    float* coef_flat = &coef[0][0];
    for (int idx = tid; idx < ROWS * Ee; idx += 256) {
        int r = idx >> 9, j = idx & (Ee - 1);
        int t = adjb[idx];
        float v;
        if (t > 0) {
            float x = ss[t - 1][r] + sd[t - 1][j];
            v = (x >= 0.f) ? x : SLOPE * x;
        } else {
            v = -1e30f;
        }
        coef_flat[idx] = v;
    }
    __syncthreads();

    // softmax per row (wave w owns rows w*8 .. w*8+7)
    int wv = tid >> 6, lane = tid & 63;
    #pragma unroll
    for (int rr = 0; rr < 8; ++rr) {
        int r = wv * 8 + rr;
        float vals[8];
        float m = -3.0e38f;
        #pragma unroll
        for (int k = 0; k < 8; ++k) {
            vals[k] = coef[r][lane + 64 * k];
            m = fmaxf(m, vals[k]);
        }
        #pragma unroll
        for (int off = 32; off; off >>= 1) m = fmaxf(m, __shfl_xor(m, off));
        float s = 0.f;
        #pragma unroll
        for (int k = 0; k < 8; ++k) {
            vals[k] = __expf(vals[k] - m);
            s += vals[k];
        }
        #pragma unroll
        for (int off = 32; off; off >>= 1) s += __shfl_xor(s, off);
        float inv = 1.f / s;
        #pragma unroll
        for (int k = 0; k < 8; ++k) coef[r][lane + 64 * k] = vals[k] * inv;
    }
    __syncthreads();

    // PV: out[row, d] = sum_j coef[row][j] * hm[n, j, d]
    const float* hmn = hm + (size_t)n * Ee * DOUT;
    int r0 = wv * 8;
    float acc[8][5];
    #pragma unroll
    for (int r = 0; r < 8; ++r)
        #pragma unroll
        for (int k = 0; k < 5; ++k) acc[r][k] = 0.f;

    for (int j = 0; j < Ee; ++j) {
        float c[8];
        #pragma unroll
        for (int r = 0; r < 8; ++r) c[r] = coef[r0 + r][j];
        #pragma unroll
        for (int k = 0; k < 5; ++k) {
            int d = lane + 64 * k;
            float h = (d < DOUT) ? hmn[(size_t)j * DOUT + d] : 0.f;
            #pragma unroll
            for (int r = 0; r < 8; ++r) acc[r][k] += c[r] * h;
        }
    }

    #pragma unroll
    for (int r = 0; r < 8; ++r) {
        #pragma unroll
        for (int k = 0; k < 5; ++k) {
            int d = lane + 64 * k;
            if (d < DOUT)
                out[((size_t)n * Ee + row0 + r0 + r) * DOUT + d] = acc[r][k];
        }
    }
}

// ---------------------------------------------------------------------------
extern "C" void kernel_launch(void* const* d_in, const int* in_sizes, int n_in,
                              void* d_out, int out_size, void* d_ws, size_t ws_size,
                              hipStream_t stream) {
    const float* input_state = (const float*)d_in[0];
    const int*   adj         = (const int*)  d_in[1];
    const float* node_mask   = (const float*)d_in[2];
    const float* query_vec   = (const float*)d_in[3];
    const float* W_type      = (const float*)d_in[4];
    const float* a_type      = (const float*)d_in[5];
    const float* qattn_W1    = (const float*)d_in[6];
    const float* qattn_W2    = (const float*)d_in[7];
    float* out = (float*)d_out;

    // workspace layout (floats): needs ~20.8 MB
    float* ws   = (float*)d_ws;
    float* g    = ws;                 // 4*32*600   = 76800
    float* u1   = g    + 76800;       // 4*32*300   = 38400
    float* u2   = u1   + 38400;       // 38400
    float* ssrc = u2   + 38400;       // 4*32*512   = 65536
    float* sdst = ssrc + 65536;       // 65536
    float* hm   = sdst + 65536;       // 32*512*300 = 4915200

    hipLaunchKernelGGL(gates_kernel, dim3(NT, Nn), dim3(256), 0, stream,
                       query_vec, qattn_W1, qattn_W2, g);
    hipLaunchKernelGGL(uvec_kernel, dim3(NT, Nn), dim3(256), 0, stream,
                       W_type, a_type, g, u1, u2);
    hipLaunchKernelGGL(sdot_kernel, dim3(Ee, Nn), dim3(64), 0, stream,
                       input_state, u1, u2, ssrc, sdst);
    hipLaunchKernelGGL(hm_kernel, dim3((Nn * Ee) / 32), dim3(256), 0, stream,
                       input_state, W_type + 3 * DIN * DOUT, node_mask, hm);
    hipLaunchKernelGGL(attn_kernel, dim3(Ee / ROWS, Nn), dim3(256), 0, stream,
                       adj, ssrc, sdst, hm, out);
}

// Round 2
// 277.760 us; speedup vs baseline: 1.2487x; 1.2487x over previous
//
#include <hip/hip_runtime.h>
#include <hip/hip_bf16.h>

// Problem constants
#define Nn   32
#define Ee   512
#define DIN  300
#define DOUT 300
#define NT   4
#define QD   300
#define SLOPE 0.2f
#define ROWS 32   // rows per block in attn kernel
#define CPAD 320  // padded d-dim for hmT (20 MFMA n-tiles of 16)

typedef __attribute__((ext_vector_type(8))) short bf16x8;
typedef __attribute__((ext_vector_type(4))) float f32x4;

__device__ inline unsigned short f2bf(float x) {
    __hip_bfloat16 h = __float2bfloat16(x);   // RNE
    return *reinterpret_cast<unsigned short*>(&h);
}
__device__ inline float bf2f(unsigned short u) {
    __hip_bfloat16 h = *reinterpret_cast<__hip_bfloat16*>(&u);
    return __bfloat162float(h);
}

// ---------------------------------------------------------------------------
// K1: gates. g[i][n][0..599] = sigmoid( relu(q[n] @ W1[i]) @ W2[i] )
__global__ __launch_bounds__(256) void gates_kernel(
    const float* __restrict__ q,    // (N, 300)
    const float* __restrict__ W1,   // (4, 300, 600)
    const float* __restrict__ W2,   // (4, 600, 600)
    float* __restrict__ g)          // (4, N, 600)
{
    int i = blockIdx.x;
    int n = blockIdx.y;
    int tid = threadIdx.x;
    __shared__ float qs[QD];
    __shared__ float t1[2 * DOUT];

    for (int k = tid; k < QD; k += 256) qs[k] = q[n * QD + k];
    __syncthreads();

    const float* W1i = W1 + (size_t)i * QD * (2 * DOUT);
    for (int j = tid; j < 2 * DOUT; j += 256) {
        float acc = 0.f;
        for (int k = 0; k < QD; ++k) acc += qs[k] * W1i[k * (2 * DOUT) + j];
        t1[j] = fmaxf(acc, 0.f);
    }
    __syncthreads();

    const float* W2i = W2 + (size_t)i * (2 * DOUT) * (2 * DOUT);
    for (int j = tid; j < 2 * DOUT; j += 256) {
        float acc = 0.f;
        for (int k = 0; k < 2 * DOUT; ++k) acc += t1[k] * W2i[k * (2 * DOUT) + j];
        g[((size_t)i * Nn + n) * (2 * DOUT) + j] = 1.f / (1.f + __expf(-acc));
    }
}

// ---------------------------------------------------------------------------
// K2: u1[i][n][k] = sum_d W[i][k][d] * g1[i][n][d] * a1[i][d]  (u2 with g2,a2)
__global__ __launch_bounds__(256) void uvec_kernel(
    const float* __restrict__ W,    // (4, 300, 300)
    const float* __restrict__ a,    // (4, 600)
    const float* __restrict__ g,    // (4, N, 600)
    float* __restrict__ u1,         // (4, N, 300)
    float* __restrict__ u2)         // (4, N, 300)
{
    int i = blockIdx.x;
    int n = blockIdx.y;
    int tid = threadIdx.x;
    __shared__ float w1[DOUT], w2[DOUT];

    const float* gi = g + ((size_t)i * Nn + n) * (2 * DOUT);
    const float* ai = a + (size_t)i * (2 * DOUT);
    for (int d = tid; d < DOUT; d += 256) {
        w1[d] = gi[d] * ai[d];
        w2[d] = gi[DOUT + d] * ai[DOUT + d];
    }
    __syncthreads();

    const float* Wi = W + (size_t)i * DIN * DOUT;
    for (int k = tid; k < DIN; k += 256) {
        float a1 = 0.f, a2 = 0.f;
        for (int d = 0; d < DOUT; ++d) {
            float w = Wi[k * DOUT + d];
            a1 += w * w1[d];
            a2 += w * w2[d];
        }
        u1[((size_t)i * Nn + n) * DIN + k] = a1;
        u2[((size_t)i * Nn + n) * DIN + k] = a2;
    }
}

// ---------------------------------------------------------------------------
// K3: ssrc[i][n][e] = input[n,e,:] . u1[i][n][:]   (sdst with u2)
__global__ __launch_bounds__(64) void sdot_kernel(
    const float* __restrict__ X,    // (N, E, 300)
    const float* __restrict__ u1,   // (4, N, 300)
    const float* __restrict__ u2,   // (4, N, 300)
    float* __restrict__ ssrc,       // (4, N, E)
    float* __restrict__ sdst)       // (4, N, E)
{
    int e = blockIdx.x;
    int n = blockIdx.y;
    int lane = threadIdx.x;
    const float* x = X + ((size_t)n * Ee + e) * DIN;

    float xv[5];
    #pragma unroll
    for (int k = 0; k < 5; ++k) {
        int d = lane + 64 * k;
        xv[k] = (d < DIN) ? x[d] : 0.f;
    }
    #pragma unroll
    for (int i = 0; i < NT; ++i) {
        const float* u1i = u1 + ((size_t)i * Nn + n) * DIN;
        const float* u2i = u2 + ((size_t)i * Nn + n) * DIN;
        float a1 = 0.f, a2 = 0.f;
        #pragma unroll
        for (int k = 0; k < 5; ++k) {
            int d = lane + 64 * k;
            if (d < DIN) { a1 += xv[k] * u1i[d]; a2 += xv[k] * u2i[d]; }
        }
        #pragma unroll
        for (int off = 32; off; off >>= 1) {
            a1 += __shfl_xor(a1, off);
            a2 += __shfl_xor(a2, off);
        }
        if (lane == 0) {
            ssrc[((size_t)i * Nn + n) * Ee + e] = a1;
            sdst[((size_t)i * Nn + n) * Ee + e] = a2;
        }
    }
}

// ---------------------------------------------------------------------------
// K4: hm[row][d] = (X[row,:] @ W3)[d] * mask[row], emitted TRANSPOSED as
// bf16 split pair:  hmT_hi/lo[n][d (pad CPAD)][j],  j = row within batch n.
__global__ __launch_bounds__(256) void hm_kernel(
    const float* __restrict__ X,    // (16384, 300)
    const float* __restrict__ W3,   // (300, 300)
    const float* __restrict__ mask, // (16384)
    unsigned short* __restrict__ hmT_hi,  // (32, CPAD, 512)
    unsigned short* __restrict__ hmT_lo)  // (32, CPAD, 512)
{
    __shared__ float smem[32 * 321];  // phase A: X tile (stride 300); phase B: hm tile (stride 321)
    int tid = threadIdx.x;
    size_t row0 = (size_t)blockIdx.x * 32;

    for (int idx = tid; idx < 32 * DIN; idx += 256)
        smem[idx] = X[row0 * DIN + idx];
    __syncthreads();

    int wv = tid >> 6, lane = tid & 63;
    int r0 = wv * 8;
    float acc[8][5];
    #pragma unroll
    for (int r = 0; r < 8; ++r)
        #pragma unroll
        for (int k = 0; k < 5; ++k) acc[r][k] = 0.f;

    for (int kk = 0; kk < DIN; ++kk) {
        float wval[5];
        #pragma unroll
        for (int k = 0; k < 5; ++k) {
            int d = lane + 64 * k;
            wval[k] = (d < DOUT) ? W3[kk * DOUT + d] : 0.f;
        }
        #pragma unroll
        for (int r = 0; r < 8; ++r) {
            float x = smem[(r0 + r) * DIN + kk];
            #pragma unroll
            for (int k = 0; k < 5; ++k) acc[r][k] += x * wval[k];
        }
    }
    __syncthreads();   // everyone done reading X tile

    // stash hm tile (mask applied, pad cols zeroed) at stride 321
    #pragma unroll
    for (int r = 0; r < 8; ++r) {
        float mk = mask[row0 + r0 + r];
        #pragma unroll
        for (int k = 0; k < 5; ++k) {
            int d = lane + 64 * k;   // 0..319
            smem[(r0 + r) * 321 + d] = (d < DOUT) ? acc[r][k] * mk : 0.f;
        }
    }
    __syncthreads();

    // transposed bf16-split write: lanes along j => coalesced
    int n  = (int)(row0 >> 9);
    int j0 = (int)(row0 & 511);
    int jj = tid & 31;
    for (int dd = tid >> 5; dd < CPAD; dd += 8) {
        float v = smem[jj * 321 + dd];
        unsigned short hi = f2bf(v);
        unsigned short lo = f2bf(v - bf2f(hi));
        size_t off = ((size_t)(n * CPAD + dd)) * Ee + j0 + jj;
        hmT_hi[off] = hi;
        hmT_lo[off] = lo;
    }
}

// ---------------------------------------------------------------------------
// K5: scores -> softmax -> split-bf16 MFMA PV for a 32-row tile of batch n.
// grid (E/ROWS, N), block 256 (4 waves)
__global__ __launch_bounds__(256, 2) void attn_kernel(
    const int*   __restrict__ adj,      // (N, E, E)
    const float* __restrict__ ssrc,     // (4, N, E)
    const float* __restrict__ sdst,     // (4, N, E)
    const unsigned short* __restrict__ hmT_hi,  // (32, CPAD, 512)
    const unsigned short* __restrict__ hmT_lo,
    float* __restrict__ out)            // (N, E, 300)
{
    int rt = blockIdx.x;
    int n  = blockIdx.y;
    int tid = threadIdx.x;
    int row0 = rt * ROWS;

    __shared__ unsigned coefT[Ee * 33];   // transposed coef [j][r], stride 33
    __shared__ float sdl[NT * Ee];
    __shared__ float ssl[NT * ROWS];

    for (int idx = tid; idx < NT * Ee; idx += 256) {
        int i = idx >> 9, j = idx & (Ee - 1);
        sdl[idx] = sdst[((size_t)i * Nn + n) * Ee + j];
    }
    for (int idx = tid; idx < NT * ROWS; idx += 256) {
        int i = idx >> 5, r = idx & 31;
        ssl[idx] = ssrc[((size_t)i * Nn + n) * Ee + row0 + r];
    }
    __syncthreads();

    // scores (write transposed)
    const int* adjb = adj + ((size_t)n * Ee + row0) * Ee;
    for (int idx = tid; idx < ROWS * Ee; idx += 256) {
        int r = idx >> 9, j = idx & (Ee - 1);
        int t = adjb[idx];
        float v;
        if (t > 0) {
            float x = ssl[(t - 1) * ROWS + r] + sdl[(t - 1) * Ee + j];
            v = (x >= 0.f) ? x : SLOPE * x;
        } else {
            v = -1e30f;
        }
        coefT[j * 33 + r] = __float_as_uint(v);
    }
    __syncthreads();

    // softmax per row (wave w owns rows w*8..w*8+7)
    int wv = tid >> 6, lane = tid & 63;
    #pragma unroll
    for (int rr = 0; rr < 8; ++rr) {
        int r = wv * 8 + rr;
        float vals[8];
        float m = -3.0e38f;
        #pragma unroll
        for (int k = 0; k < 8; ++k) {
            vals[k] = __uint_as_float(coefT[(lane + 64 * k) * 33 + r]);
            m = fmaxf(m, vals[k]);
        }
        #pragma unroll
        for (int off = 32; off; off >>= 1) m = fmaxf(m, __shfl_xor(m, off));
        float s = 0.f;
        #pragma unroll
        for (int k = 0; k < 8; ++k) {
            vals[k] = __expf(vals[k] - m);
            s += vals[k];
        }
        #pragma unroll
        for (int off = 32; off; off >>= 1) s += __shfl_xor(s, off);
        float inv = 1.f / s;
        #pragma unroll
        for (int k = 0; k < 8; ++k)
            coefT[(lane + 64 * k) * 33 + r] = __float_as_uint(vals[k] * inv);
    }
    __syncthreads();

    // pack coef -> (bf16_hi << 16) | bf16_lo, in place
    for (int idx = tid; idx < Ee * ROWS; idx += 256) {
        int j = idx >> 5, r = idx & 31;
        float v = __uint_as_float(coefT[j * 33 + r]);
        unsigned short hi = f2bf(v);
        unsigned short lo = f2bf(v - bf2f(hi));
        coefT[j * 33 + r] = ((unsigned)hi << 16) | (unsigned)lo;
    }
    __syncthreads();

    // PV:  out_tile(32 x 300) = coef(32 x 512) @ hm(512 x 300), split bf16.
    // Wave wv owns n-tiles {wv, wv+4, wv+8, wv+12, wv+16} (CPAD/16 = 20 tiles).
    int g  = lane >> 4;
    int cr = lane & 15;
    f32x4 acc[5][2];
    #pragma unroll
    for (int a = 0; a < 5; ++a)
        #pragma unroll
        for (int m = 0; m < 2; ++m) acc[a][m] = (f32x4){0.f, 0.f, 0.f, 0.f};

    for (int ks = 0; ks < 16; ++ks) {
        int k0 = ks * 32;
        bf16x8 ahi[2], alo[2];
        #pragma unroll
        for (int m = 0; m < 2; ++m) {
            #pragma unroll
            for (int j = 0; j < 8; ++j) {
                unsigned v = coefT[(k0 + 8 * g + j) * 33 + m * 16 + cr];
                ahi[m][j] = (short)(v >> 16);
                alo[m][j] = (short)(v & 0xffffu);
            }
        }
        #pragma unroll
        for (int ntl = 0; ntl < 5; ++ntl) {
            int c = (wv + 4 * ntl) * 16 + cr;
            size_t off = ((size_t)(n * CPAD + c)) * Ee + k0 + 8 * g;
            bf16x8 bhi = *(const bf16x8*)(hmT_hi + off);
            bf16x8 blo = *(const bf16x8*)(hmT_lo + off);
            #pragma unroll
            for (int m = 0; m < 2; ++m) {
                acc[ntl][m] = __builtin_amdgcn_mfma_f32_16x16x32_bf16(ahi[m], bhi, acc[ntl][m], 0, 0, 0);
                acc[ntl][m] = __builtin_amdgcn_mfma_f32_16x16x32_bf16(ahi[m], blo, acc[ntl][m], 0, 0, 0);
                acc[ntl][m] = __builtin_amdgcn_mfma_f32_16x16x32_bf16(alo[m], bhi, acc[ntl][m], 0, 0, 0);
            }
        }
    }

    // epilogue: D[row=4g+q][col=cr] per 16x16 tile
    #pragma unroll
    for (int ntl = 0; ntl < 5; ++ntl) {
        int c = (wv + 4 * ntl) * 16 + cr;
        if (c < DOUT) {
            #pragma unroll
            for (int m = 0; m < 2; ++m) {
                #pragma unroll
                for (int q = 0; q < 4; ++q) {
                    int erow = row0 + m * 16 + 4 * g + q;
                    out[((size_t)n * Ee + erow) * DOUT + c] = acc[ntl][m][q];
                }
            }
        }
    }
}

// ---------------------------------------------------------------------------
extern "C" void kernel_launch(void* const* d_in, const int* in_sizes, int n_in,
                              void* d_out, int out_size, void* d_ws, size_t ws_size,
                              hipStream_t stream) {
    const float* input_state = (const float*)d_in[0];
    const int*   adj         = (const int*)  d_in[1];
    const float* node_mask   = (const float*)d_in[2];
    const float* query_vec   = (const float*)d_in[3];
    const float* W_type      = (const float*)d_in[4];
    const float* a_type      = (const float*)d_in[5];
    const float* qattn_W1    = (const float*)d_in[6];
    const float* qattn_W2    = (const float*)d_in[7];
    float* out = (float*)d_out;

    // workspace layout
    float* ws   = (float*)d_ws;
    float* g    = ws;                 // 4*32*600   = 76800
    float* u1   = g    + 76800;       // 4*32*300   = 38400
    float* u2   = u1   + 38400;       // 38400
    float* ssrc = u2   + 38400;       // 4*32*512   = 65536
    float* sdst = ssrc + 65536;       // 65536
    unsigned short* hmT_hi = (unsigned short*)(sdst + 65536);  // 32*320*512 u16
    unsigned short* hmT_lo = hmT_hi + (size_t)Nn * CPAD * Ee;  // 32*320*512 u16

    hipLaunchKernelGGL(gates_kernel, dim3(NT, Nn), dim3(256), 0, stream,
                       query_vec, qattn_W1, qattn_W2, g);
    hipLaunchKernelGGL(uvec_kernel, dim3(NT, Nn), dim3(256), 0, stream,
                       W_type, a_type, g, u1, u2);
    hipLaunchKernelGGL(sdot_kernel, dim3(Ee, Nn), dim3(64), 0, stream,
                       input_state, u1, u2, ssrc, sdst);
    hipLaunchKernelGGL(hm_kernel, dim3((Nn * Ee) / 32), dim3(256), 0, stream,
                       input_state, W_type + 3 * DIN * DOUT, node_mask, hmT_hi, hmT_lo);
    hipLaunchKernelGGL(attn_kernel, dim3(Ee / ROWS, Nn), dim3(256), 0, stream,
                       adj, ssrc, sdst, hmT_hi, hmT_lo, out);
}